// Round 1
// baseline (929.071 us; speedup 1.0000x reference)
//
#include <hip/hip_runtime.h>
#include <hip/hip_bf16.h>
#include <cstdint>

// Problem: BatchNorm2d(train stats) -> sign -> conv3x3(sign(w), pad=1) -> +b -> relu
// x[64,256,56,56] f32, w[256,256,3,3] f32, out[64,256,56,56] f32.
// Implemented as XNOR-popcount binary conv:
//   bit(c) = (a_c * x + c_c > 0), a_c = gamma*rsqrt(var+eps), c_c = beta - a_c*mean
//   dot over 256 ch x 9 taps = 256*V - 2*D + 2*sum_invalid popc(w_tap)
// where D = popcount over all 9 taps with zero-padded activation bits.

#define N_IMG 64
#define C_CH 256
#define HW 3136
#define W_IMG 56

// ---------------- Kernel A: per-channel mean/var -> fold BN into (a, c) ----------------
__global__ void stats_kernel(const float* __restrict__ x, const float* __restrict__ gamma,
                             const float* __restrict__ beta,
                             float* __restrict__ scaleA, float* __restrict__ biasC) {
    const int c = blockIdx.x;          // 256 blocks
    const int tid = threadIdx.x;       // 1024 threads
    float s = 0.f, q = 0.f;
    const float* xc = x + (size_t)c * HW;
    for (int n = 0; n < N_IMG; ++n) {
        const float* xn = xc + (size_t)n * C_CH * HW;
        for (int r = tid; r < HW; r += 1024) {
            float v = xn[r];
            s += v;
            q = fmaf(v, v, q);
        }
    }
    __shared__ double ls[1024];
    __shared__ double lq[1024];
    ls[tid] = (double)s; lq[tid] = (double)q;
    __syncthreads();
    for (int off = 512; off > 0; off >>= 1) {
        if (tid < off) { ls[tid] += ls[tid + off]; lq[tid] += lq[tid + off]; }
        __syncthreads();
    }
    if (tid == 0) {
        const double M = (double)N_IMG * (double)HW;
        double mean = ls[0] / M;
        double var  = lq[0] / M - mean * mean;
        float inv = (float)(1.0 / sqrt(var + 1e-5));
        float a = gamma[c] * inv;
        float cc = beta[c] - (float)mean * a;
        scaleA[c] = a;
        biasC[c] = cc;
    }
}

// ---------------- Kernel C: pack sign(w) into bits + per-tap popcounts ----------------
// wpack layout: [co][tap][8 x u32]  (bit ci of word ci>>5)
__global__ void wpack_kernel(const float* __restrict__ w, uint32_t* __restrict__ wpack,
                             int* __restrict__ wtap) {
    int id = blockIdx.x * 256 + threadIdx.x;   // 2304 = 256 co * 9 taps
    if (id >= 2304) return;
    int co = id / 9, t = id - co * 9;
    const float* wp = w + (size_t)co * 2304 + t;   // w[co][ci][t], ci stride 9
    int pc = 0;
#pragma unroll
    for (int wd = 0; wd < 8; ++wd) {
        uint32_t bits = 0;
        for (int i = 0; i < 32; ++i) {
            float v = wp[(size_t)(wd * 32 + i) * 9];
            bits |= (v > 0.f ? (1u << i) : 0u);
        }
        wpack[(size_t)id * 8 + wd] = bits;
        pc += __popc(bits);
    }
    wtap[id] = pc;
}

// ---------------- Kernel B: binarize + pack activations ----------------
// apack layout: [n][y][x][8 x u32]  (32B per pixel, channel bits contiguous)
__global__ void binarize_kernel(const float* __restrict__ x, const float* __restrict__ A,
                                const float* __restrict__ C, uint32_t* __restrict__ apack) {
    int p = blockIdx.x * 256 + threadIdx.x;    // 200704 pixels
    if (p >= N_IMG * HW) return;
    int n = p / HW;
    int r = p - n * HW;
    const float* xp = x + (size_t)n * C_CH * HW + r;
    uint32_t wbits[8];
#pragma unroll
    for (int wo = 0; wo < 8; ++wo) {
        uint32_t bits = 0;
        for (int i = 0; i < 32; ++i) {
            int c = wo * 32 + i;
            float v = fmaf(A[c], xp[(size_t)c * HW], C[c]);
            bits |= (v > 0.f ? (1u << i) : 0u);
        }
        wbits[wo] = bits;
    }
    uint4* dst = (uint4*)(apack + (size_t)p * 8);
    dst[0] = make_uint4(wbits[0], wbits[1], wbits[2], wbits[3]);
    dst[1] = make_uint4(wbits[4], wbits[5], wbits[6], wbits[7]);
}

// ---------------- Kernel D: XNOR-popcount conv ----------------
// Tile: 32x (x) * 8y pixels per block, 8 output channels per block.
// grid: (2 xtiles, 7 ytiles, 64 n * 32 cog)
#define COG 8
__global__ __launch_bounds__(256, 2) void conv_kernel(
    const uint32_t* __restrict__ apack, const uint32_t* __restrict__ wpack,
    const int* __restrict__ wtap, const float* __restrict__ bias,
    float* __restrict__ out) {
    const int xt = blockIdx.x, yt = blockIdx.y;
    const int z = blockIdx.z;
    const int n = z >> 5;      // /32
    const int cg = z & 31;
    const int tid = threadIdx.x;
    const int tx = tid & 31, ty = tid >> 5;
    const int gx0 = xt * 32, gy0 = yt * 8;

    // halo: 10 rows x 34 cols x 32B = 10880B
    __shared__ __align__(16) uint32_t lds[10 * 34 * 8];
    const int HP = 10 * 34;
    for (int i = tid; i < HP * 2; i += 256) {
        int pix = i >> 1, h = i & 1;
        int r = pix / 34, c0 = pix - r * 34;
        int gy = gy0 - 1 + r, gx = gx0 - 1 + c0;
        uint4 v = make_uint4(0u, 0u, 0u, 0u);
        if (gy >= 0 && gy < W_IMG && gx >= 0 && gx < W_IMG) {
            const uint4* src = (const uint4*)(apack + ((size_t)(n * HW + gy * W_IMG + gx)) * 8);
            v = src[h];
        }
        ((uint4*)lds)[pix * 2 + h] = v;
    }
    __syncthreads();

    // preload this thread's 3x3 window (9 taps x 4 u64 = 72 VGPRs)
    uint64_t a[9][4];
    const uint64_t* l64 = (const uint64_t*)lds;
#pragma unroll
    for (int dy = 0; dy < 3; ++dy)
#pragma unroll
        for (int dx = 0; dx < 3; ++dx) {
            int p = (ty + dy) * 34 + (tx + dx);
#pragma unroll
            for (int wd = 0; wd < 4; ++wd) a[dy * 3 + dx][wd] = l64[p * 4 + wd];
        }

    // weights: block-uniform -> scalar loads
    const uint64_t* w64 = (const uint64_t*)wpack + (size_t)cg * COG * 9 * 4;
    int acc[COG];
#pragma unroll
    for (int co = 0; co < COG; ++co) {
        int s = 0;
#pragma unroll
        for (int t = 0; t < 9; ++t) {
#pragma unroll
            for (int wd = 0; wd < 4; ++wd)
                s += __popcll(a[t][wd] ^ w64[(co * 9 + t) * 4 + wd]);
        }
        acc[co] = s;
    }

    const int gx = gx0 + tx, gy = gy0 + ty;   // gy < 56 always (7*8)
    if (gx >= W_IMG) return;

    int vy = 3 - (gy == 0) - (gy == W_IMG - 1);
    int vx = 3 - (gx == 0) - (gx == W_IMG - 1);
    int V = vy * vx;

    int corr[COG];
#pragma unroll
    for (int co = 0; co < COG; ++co) corr[co] = 0;
    if (V != 9) {
#pragma unroll
        for (int t = 0; t < 9; ++t) {
            int dy = t / 3 - 1, dx = t % 3 - 1;
            bool inv = (gy + dy < 0) || (gy + dy > W_IMG - 1) || (gx + dx < 0) || (gx + dx > W_IMG - 1);
            if (inv) {
#pragma unroll
                for (int co = 0; co < COG; ++co) corr[co] += wtap[(cg * COG + co) * 9 + t];
            }
        }
    }

#pragma unroll
    for (int co = 0; co < COG; ++co) {
        int cofull = cg * COG + co;
        float y = (float)(256 * V - 2 * acc[co] + 2 * corr[co]) + bias[cofull];
        out[((size_t)(n * C_CH + cofull)) * HW + gy * W_IMG + gx] = fmaxf(y, 0.f);
    }
}

extern "C" void kernel_launch(void* const* d_in, const int* in_sizes, int n_in,
                              void* d_out, int out_size, void* d_ws, size_t ws_size,
                              hipStream_t stream) {
    const float* x     = (const float*)d_in[0];
    const float* gamma = (const float*)d_in[1];
    const float* beta  = (const float*)d_in[2];
    const float* w     = (const float*)d_in[3];
    const float* b     = (const float*)d_in[4];
    float* out = (float*)d_out;

    char* ws = (char*)d_ws;
    float*    scaleA = (float*)(ws);               // 256 f
    float*    biasC  = (float*)(ws + 1024);        // 256 f
    uint32_t* wpack  = (uint32_t*)(ws + 2048);     // 18432 u32 = 73728B
    int*      wtap   = (int*)(ws + 2048 + 73728);  // 2304 int
    uint32_t* apack  = (uint32_t*)(ws + (1 << 17)); // 200704*8 u32 = 6.4MB

    stats_kernel<<<C_CH, 1024, 0, stream>>>(x, gamma, beta, scaleA, biasC);
    wpack_kernel<<<9, 256, 0, stream>>>(w, wpack, wtap);
    binarize_kernel<<<(N_IMG * HW) / 256, 256, 0, stream>>>(x, scaleA, biasC, apack);
    conv_kernel<<<dim3(2, 7, N_IMG * 32), 256, 0, stream>>>(apack, wpack, wtap, b, out);
}